// Round 1
// baseline (572.949 us; speedup 1.0000x reference)
//
#include <hip/hip_runtime.h>
#include <math.h>

#define HDIM 64

typedef __attribute__((ext_vector_type(8))) short short8;
typedef __attribute__((ext_vector_type(4))) float floatx4;
typedef unsigned short ushort_t;

#define MFMA16(a, b, c) __builtin_amdgcn_mfma_f32_16x16x32_bf16(a, b, c, 0, 0, 0)

__device__ __forceinline__ ushort_t f2bf(float f) {
  union { float f; unsigned u; } v; v.f = f;
  unsigned u = v.u;
  return (ushort_t)((u + 0x7FFFu + ((u >> 16) & 1u)) >> 16);
}

__device__ __forceinline__ float silu1(float v) { return __fdividef(v, 1.0f + __expf(-v)); }
__device__ __forceinline__ float tanh1(float v) {
  float t = __expf(2.0f * v);
  return 1.0f - __fdividef(2.0f, t + 1.0f);
}

// ---------------- fp32 -> bf16 conversion (x then pe, one launch) ----------------
__global__ void kcvt2(const float* __restrict__ x, const float* __restrict__ pe,
                      ushort_t* __restrict__ d, int n) {   // n = elements per tensor
  int i = (blockIdx.x * 256 + threadIdx.x) * 8;
  if (i < 2 * n) {
    const float* sp = (i < n) ? (x + i) : (pe + (i - n));
    float4 a = *(const float4*)sp;
    float4 b = *(const float4*)(sp + 4);
    union { ushort_t u[8]; uint4 v; } r;
    r.u[0] = f2bf(a.x); r.u[1] = f2bf(a.y); r.u[2] = f2bf(a.z); r.u[3] = f2bf(a.w);
    r.u[4] = f2bf(b.x); r.u[5] = f2bf(b.y); r.u[6] = f2bf(b.z); r.u[7] = f2bf(b.w);
    *(uint4*)(d + i) = r.v;
  }
}

// ---------------- counting sort of edges by receiver ----------------
// int64 vs int32 detection done on-device (same trick as previous kedge).
__global__ void khist(const int* __restrict__ idx32, int* __restrict__ cnt, int E) {
  const int m = ((idx32[1] | idx32[3] | idx32[5] | idx32[7]) == 0) ? 2 : 1;
  for (int e = blockIdx.x * 256 + threadIdx.x; e < E; e += gridDim.x * 256) {
    int r = idx32[(size_t)m * (E + e)];
    atomicAdd(&cnt[r], 1);
  }
}

__global__ __launch_bounds__(1024) void kscan(int* __restrict__ cnt, int n) {
  __shared__ int part[1024];
  const int tid = threadIdx.x;
  const int per = (n + 1023) >> 10;
  const int lo = tid * per, hi = min(lo + per, n);
  int s = 0;
  for (int i = lo; i < hi; ++i) s += cnt[i];
  part[tid] = s;
  __syncthreads();
  for (int d = 1; d < 1024; d <<= 1) {
    int v = (tid >= d) ? part[tid - d] : 0;
    __syncthreads();
    part[tid] += v;
    __syncthreads();
  }
  int run = (tid == 0) ? 0 : part[tid - 1];   // exclusive base for this chunk
  for (int i = lo; i < hi; ++i) { int c = cnt[i]; cnt[i] = run; run += c; }
}

__global__ void kscatter(const int* __restrict__ idx32, int* __restrict__ cnt,
                         int2* __restrict__ sedge, int E) {
  const int m = ((idx32[1] | idx32[3] | idx32[5] | idx32[7]) == 0) ? 2 : 1;
  for (int e = blockIdx.x * 256 + threadIdx.x; e < E; e += gridDim.x * 256) {
    int s = idx32[(size_t)m * e];
    int r = idx32[(size_t)m * (E + e)];
    int p = atomicAdd(&cnt[r], 1);
    sedge[p] = make_int2(s, r);
  }
}

// ================= merged edge kernel (sorted-edge, segment-reduced atomics) =================
// msg: state=[x_s,pe_s,x_r,pe_r,dist] (K=257), silu. pos: state=[pe_s,pe_r,dist] (K=129), tanh.
// Edges are sorted by receiver: within each 16-edge MFMA sub-tile we reduce message rows
// per receiver-segment in registers (masked fma + shfl_xor over quads), carry a pending
// per-column accumulator across sub-tiles, and emit one 256B full-row atomic per distinct
// receiver per tile (~5/tile) instead of 64/tile. LDS 77.5 KB -> 2 blocks/CU.
__global__ __launch_bounds__(256, 2) void kedge(
    const ushort_t* __restrict__ xb, const ushort_t* __restrict__ peb,
    const float* __restrict__ pos, const int2* __restrict__ sedge,
    const float* __restrict__ mw1, const float* __restrict__ mb1,
    const float* __restrict__ mw2, const float* __restrict__ mb2,
    const float* __restrict__ pw1, const float* __restrict__ pb1,
    const float* __restrict__ pw2, const float* __restrict__ pb2,
    float* __restrict__ aggr, float* __restrict__ aggrp, int E) {
  __shared__ ushort_t w1m[16384];          // 32 KB  msg w1 rows 0..255, B-frag layout
  __shared__ ushort_t w1p[8192];           // 16 KB  pos w1 rows 0..127
  __shared__ ushort_t w2m[4096];           // 8 KB
  __shared__ ushort_t w2p[4096];           // 8 KB
  __shared__ ushort_t hmat[4][1152];       // 9.2 KB: per-wave 16x72 bf16 chunk
  __shared__ int   srow[4][64];
  __shared__ int   rrow[4][64];
  __shared__ float ddv[4][64];
  __shared__ float cb1m[64], cb2m[64], wdm[64];
  __shared__ float cb1p[64], cb2p[64], wdp[64];

  for (int i = threadIdx.x; i < 257 * 64; i += 256) {
    int k = i >> 6, n = i & 63; float v = mw1[i];
    if (k < 256) w1m[(((k >> 5) * 4 + ((k >> 3) & 3)) * 64 + n) * 8 + (k & 7)] = f2bf(v);
    else wdm[n] = v;                       // dist row stays fp32
  }
  for (int i = threadIdx.x; i < 129 * 64; i += 256) {
    int k = i >> 6, n = i & 63; float v = pw1[i];
    if (k < 128) w1p[(((k >> 5) * 4 + ((k >> 3) & 3)) * 64 + n) * 8 + (k & 7)] = f2bf(v);
    else wdp[n] = v;
  }
  for (int i = threadIdx.x; i < 64 * 64; i += 256) {
    int k = i >> 6, n = i & 63;
    int off = (((k >> 5) * 4 + ((k >> 3) & 3)) * 64 + n) * 8 + (k & 7);
    w2m[off] = f2bf(mw2[i]);
    w2p[off] = f2bf(pw2[i]);
  }
  if (threadIdx.x < 64) {
    cb1m[threadIdx.x] = mb1[threadIdx.x]; cb2m[threadIdx.x] = mb2[threadIdx.x];
    cb1p[threadIdx.x] = pb1[threadIdx.x]; cb2p[threadIdx.x] = pb2[threadIdx.x];
  }
  __syncthreads();

  const int lane = threadIdx.x & 63;
  const int wv   = threadIdx.x >> 6;
  const int n15  = lane & 15;
  const int quad = lane >> 4;
  const int gw = blockIdx.x * 4 + wv;
  ushort_t* hm = &hmat[wv][0];

  for (int base = gw * 64; base < E; base += gridDim.x * 256) {
    {
      int e = base + lane, ec = min(e, E - 1);
      int2 sr = sedge[ec];
      srow[wv][lane] = sr.x; rrow[wv][lane] = sr.y;
      float dx = pos[3 * sr.x + 0] - pos[3 * sr.y + 0];
      float dy = pos[3 * sr.x + 1] - pos[3 * sr.y + 1];
      float dz = pos[3 * sr.x + 2] - pos[3 * sr.y + 2];
      ddv[wv][lane] = sqrtf(dx * dx + dy * dy + dz * dz);
    }
    int sm[4], rm[4];
#pragma unroll
    for (int mt = 0; mt < 4; ++mt) {
      sm[mt] = srow[wv][mt * 16 + n15];
      rm[mt] = rrow[wv][mt * 16 + n15];
    }

    // ================= message MLP phase (silu) =================
    {
      floatx4 acc[4][4];
#pragma unroll
      for (int mt = 0; mt < 4; ++mt)
#pragma unroll
        for (int reg = 0; reg < 4; ++reg) {
          float dd = ddv[wv][mt * 16 + quad * 4 + reg];
#pragma unroll
          for (int nt = 0; nt < 4; ++nt)
            acc[mt][nt][reg] = cb1m[nt * 16 + n15] + dd * wdm[nt * 16 + n15];
        }

#pragma unroll
      for (int ks = 0; ks < 8; ++ks) {
        const int seg = ks >> 1, half = ks & 1;
        const ushort_t* sb = (seg == 0 || seg == 2) ? xb : peb;
        short8 B[4];
#pragma unroll
        for (int nt = 0; nt < 4; ++nt)
          B[nt] = *(const short8*)&w1m[((ks * 4 + quad) * 64 + nt * 16 + n15) * 8];
#pragma unroll
        for (int mt = 0; mt < 4; ++mt) {
          int row = (seg < 2) ? sm[mt] : rm[mt];
          short8 A = *(const short8*)(sb + (size_t)row * 64 + half * 32 + quad * 8);
#pragma unroll
          for (int nt = 0; nt < 4; ++nt)
            acc[mt][nt] = MFMA16(A, B[nt], acc[mt][nt]);
        }
      }

      int pendR = -1; float pendV = 0.0f;
#pragma unroll
      for (int mt = 0; mt < 4; ++mt) {
#pragma unroll
        for (int nt = 0; nt < 4; ++nt)
#pragma unroll
          for (int reg = 0; reg < 4; ++reg)
            hm[(quad * 4 + reg) * 72 + nt * 16 + n15] = f2bf(silu1(acc[mt][nt][reg]));

        floatx4 o[4];
#pragma unroll
        for (int nt = 0; nt < 4; ++nt) {
          float bv = cb2m[nt * 16 + n15];
#pragma unroll
          for (int reg = 0; reg < 4; ++reg) o[nt][reg] = bv;
        }
#pragma unroll
        for (int ks = 0; ks < 2; ++ks) {
          short8 A = *(const short8*)&hm[n15 * 72 + ks * 32 + quad * 8];
          short8 B[4];
#pragma unroll
          for (int nt = 0; nt < 4; ++nt)
            B[nt] = *(const short8*)&w2m[((ks * 4 + quad) * 64 + nt * 16 + n15) * 8];
#pragma unroll
          for (int nt = 0; nt < 4; ++nt)
            o[nt] = MFMA16(A, B[nt], o[nt]);
        }

        // outer activation in-place
#pragma unroll
        for (int nt = 0; nt < 4; ++nt)
#pragma unroll
          for (int reg = 0; reg < 4; ++reg)
            o[nt][reg] = silu1(o[nt][reg]);

        // segmented reduction over this sub-tile's 16 sorted edges
        int rem = E - (base + mt * 16);
        unsigned vmask = rem >= 16 ? 0xFFFFu : (rem <= 0 ? 0u : ((1u << rem) - 1u));
        int e0 = 0;
        while (e0 < 16) {
          const int r0 = rrow[wv][mt * 16 + e0];
          int e1 = e0 + 1;
          while (e1 < 16 && rrow[wv][mt * 16 + e1] == r0) ++e1;
          unsigned segm = (((e1 == 16) ? 0xFFFFu : ((1u << e1) - 1u)) & ~((1u << e0) - 1u)) & vmask;
          if (segm) {
            float s0 = 0.0f, s1 = 0.0f, s2 = 0.0f, s3 = 0.0f;
#pragma unroll
            for (int reg = 0; reg < 4; ++reg) {
              float msk = (float)((segm >> (quad * 4 + reg)) & 1u);
              s0 = fmaf(msk, o[0][reg], s0);
              s1 = fmaf(msk, o[1][reg], s1);
              s2 = fmaf(msk, o[2][reg], s2);
              s3 = fmaf(msk, o[3][reg], s3);
            }
            s0 += __shfl_xor(s0, 16); s0 += __shfl_xor(s0, 32);
            s1 += __shfl_xor(s1, 16); s1 += __shfl_xor(s1, 32);
            s2 += __shfl_xor(s2, 16); s2 += __shfl_xor(s2, 32);
            s3 += __shfl_xor(s3, 16); s3 += __shfl_xor(s3, 32);
            float v = (quad & 2) ? ((quad & 1) ? s3 : s2) : ((quad & 1) ? s1 : s0);
            if (r0 != pendR) {
              if (pendR >= 0) unsafeAtomicAdd(aggr + (size_t)pendR * 64 + lane, pendV);
              pendR = r0; pendV = v;
            } else {
              pendV += v;
            }
          }
          e0 = e1;
        }
      }
      if (pendR >= 0) unsafeAtomicAdd(aggr + (size_t)pendR * 64 + lane, pendV);
    }

    // ================= positional MLP phase (tanh) =================
    {
      floatx4 acc[4][4];
#pragma unroll
      for (int mt = 0; mt < 4; ++mt)
#pragma unroll
        for (int reg = 0; reg < 4; ++reg) {
          float dd = ddv[wv][mt * 16 + quad * 4 + reg];
#pragma unroll
          for (int nt = 0; nt < 4; ++nt)
            acc[mt][nt][reg] = cb1p[nt * 16 + n15] + dd * wdp[nt * 16 + n15];
        }

#pragma unroll
      for (int ks = 0; ks < 4; ++ks) {
        const int seg = ks >> 1, half = ks & 1;
        short8 B[4];
#pragma unroll
        for (int nt = 0; nt < 4; ++nt)
          B[nt] = *(const short8*)&w1p[((ks * 4 + quad) * 64 + nt * 16 + n15) * 8];
#pragma unroll
        for (int mt = 0; mt < 4; ++mt) {
          int row = (seg == 0) ? sm[mt] : rm[mt];
          short8 A = *(const short8*)(peb + (size_t)row * 64 + half * 32 + quad * 8);
#pragma unroll
          for (int nt = 0; nt < 4; ++nt)
            acc[mt][nt] = MFMA16(A, B[nt], acc[mt][nt]);
        }
      }

      int pendR = -1; float pendV = 0.0f;
#pragma unroll
      for (int mt = 0; mt < 4; ++mt) {
#pragma unroll
        for (int nt = 0; nt < 4; ++nt)
#pragma unroll
          for (int reg = 0; reg < 4; ++reg)
            hm[(quad * 4 + reg) * 72 + nt * 16 + n15] = f2bf(tanh1(acc[mt][nt][reg]));

        floatx4 o[4];
#pragma unroll
        for (int nt = 0; nt < 4; ++nt) {
          float bv = cb2p[nt * 16 + n15];
#pragma unroll
          for (int reg = 0; reg < 4; ++reg) o[nt][reg] = bv;
        }
#pragma unroll
        for (int ks = 0; ks < 2; ++ks) {
          short8 A = *(const short8*)&hm[n15 * 72 + ks * 32 + quad * 8];
          short8 B[4];
#pragma unroll
          for (int nt = 0; nt < 4; ++nt)
            B[nt] = *(const short8*)&w2p[((ks * 4 + quad) * 64 + nt * 16 + n15) * 8];
#pragma unroll
          for (int nt = 0; nt < 4; ++nt)
            o[nt] = MFMA16(A, B[nt], o[nt]);
        }

#pragma unroll
        for (int nt = 0; nt < 4; ++nt)
#pragma unroll
          for (int reg = 0; reg < 4; ++reg)
            o[nt][reg] = tanh1(o[nt][reg]);

        int rem = E - (base + mt * 16);
        unsigned vmask = rem >= 16 ? 0xFFFFu : (rem <= 0 ? 0u : ((1u << rem) - 1u));
        int e0 = 0;
        while (e0 < 16) {
          const int r0 = rrow[wv][mt * 16 + e0];
          int e1 = e0 + 1;
          while (e1 < 16 && rrow[wv][mt * 16 + e1] == r0) ++e1;
          unsigned segm = (((e1 == 16) ? 0xFFFFu : ((1u << e1) - 1u)) & ~((1u << e0) - 1u)) & vmask;
          if (segm) {
            float s0 = 0.0f, s1 = 0.0f, s2 = 0.0f, s3 = 0.0f;
#pragma unroll
            for (int reg = 0; reg < 4; ++reg) {
              float msk = (float)((segm >> (quad * 4 + reg)) & 1u);
              s0 = fmaf(msk, o[0][reg], s0);
              s1 = fmaf(msk, o[1][reg], s1);
              s2 = fmaf(msk, o[2][reg], s2);
              s3 = fmaf(msk, o[3][reg], s3);
            }
            s0 += __shfl_xor(s0, 16); s0 += __shfl_xor(s0, 32);
            s1 += __shfl_xor(s1, 16); s1 += __shfl_xor(s1, 32);
            s2 += __shfl_xor(s2, 16); s2 += __shfl_xor(s2, 32);
            s3 += __shfl_xor(s3, 16); s3 += __shfl_xor(s3, 32);
            float v = (quad & 2) ? ((quad & 1) ? s3 : s2) : ((quad & 1) ? s1 : s0);
            if (r0 != pendR) {
              if (pendR >= 0) unsafeAtomicAdd(aggrp + (size_t)pendR * 64 + lane, pendV);
              pendR = r0; pendV = v;
            } else {
              pendV += v;
            }
          }
          e0 = e1;
        }
      }
      if (pendR >= 0) unsafeAtomicAdd(aggrp + (size_t)pendR * 64 + lane, pendV);
    }
  }
}

// ================= node kernel: update MLP via MFMA =================
// update_in = [x, pe, aggr] (K=192), silu inner, NO outer act. 64-node x 64-out wave tile.
__global__ __launch_bounds__(256, 2) void knode_upd(
    const ushort_t* __restrict__ xb, const ushort_t* __restrict__ peb,
    const float* aggr,
    const float* __restrict__ w1, const float* __restrict__ b1,
    const float* __restrict__ w2, const float* __restrict__ b2,
    float* outp, int N) {
  __shared__ ushort_t w1b[12288];          // 24 KB: 192 k-rows, B-frag layout
  __shared__ ushort_t w2b[4096];           // 8 KB
  __shared__ ushort_t hmat[4][4608];       // 36.9 KB: full 64x72 per wave
  __shared__ float cb1[64], cb2[64];

  for (int i = threadIdx.x; i < 192 * 64; i += 256) {
    int k = i >> 6, n = i & 63;
    w1b[(((k >> 5) * 4 + ((k >> 3) & 3)) * 64 + n) * 8 + (k & 7)] = f2bf(w1[i]);
  }
  for (int i = threadIdx.x; i < 64 * 64; i += 256) {
    int k = i >> 6, n = i & 63;
    w2b[(((k >> 5) * 4 + ((k >> 3) & 3)) * 64 + n) * 8 + (k & 7)] = f2bf(w2[i]);
  }
  if (threadIdx.x < 64) { cb1[threadIdx.x] = b1[threadIdx.x]; cb2[threadIdx.x] = b2[threadIdx.x]; }
  __syncthreads();

  const int lane = threadIdx.x & 63;
  const int wv   = threadIdx.x >> 6;
  const int n15  = lane & 15;
  const int quad = lane >> 4;
  const int gw   = blockIdx.x * 4 + wv;
  ushort_t* hm = &hmat[wv][0];

  for (int base = gw * 64; base < N; base += gridDim.x * 256) {
    floatx4 acc[4][4];
#pragma unroll
    for (int mt = 0; mt < 4; ++mt)
#pragma unroll
      for (int nt = 0; nt < 4; ++nt) {
        float bv = cb1[nt * 16 + n15];
#pragma unroll
        for (int reg = 0; reg < 4; ++reg) acc[mt][nt][reg] = bv;
      }

    // layer 1: K=192 in 6 steps of 32 (seg 0: x, 1: pe, 2: aggr fp32->bf16)
#pragma unroll
    for (int ks = 0; ks < 6; ++ks) {
      const int seg = ks >> 1, half = ks & 1;
      short8 B[4];
#pragma unroll
      for (int nt = 0; nt < 4; ++nt)
        B[nt] = *(const short8*)&w1b[((ks * 4 + quad) * 64 + nt * 16 + n15) * 8];
#pragma unroll
      for (int mt = 0; mt < 4; ++mt) {
        int row = min(base + mt * 16 + n15, N - 1);
        short8 A;
        if (seg == 0) {
          A = *(const short8*)(xb + (size_t)row * 64 + half * 32 + quad * 8);
        } else if (seg == 1) {
          A = *(const short8*)(peb + (size_t)row * 64 + half * 32 + quad * 8);
        } else {
          const float* ap = aggr + (size_t)row * 64 + half * 32 + quad * 8;
          float4 f0 = *(const float4*)ap;
          float4 f1 = *(const float4*)(ap + 4);
          union { ushort_t u[8]; short8 s; } pk;
          pk.u[0] = f2bf(f0.x); pk.u[1] = f2bf(f0.y); pk.u[2] = f2bf(f0.z); pk.u[3] = f2bf(f0.w);
          pk.u[4] = f2bf(f1.x); pk.u[5] = f2bf(f1.y); pk.u[6] = f2bf(f1.z); pk.u[7] = f2bf(f1.w);
          A = pk.s;
        }
#pragma unroll
        for (int nt = 0; nt < 4; ++nt)
          acc[mt][nt] = MFMA16(A, B[nt], acc[mt][nt]);
      }
    }

    // epilogue 1: silu -> bf16 h-matrix (full 64x72)
#pragma unroll
    for (int mt = 0; mt < 4; ++mt)
#pragma unroll
      for (int nt = 0; nt < 4; ++nt)
#pragma unroll
        for (int reg = 0; reg < 4; ++reg)
          hm[(mt * 16 + quad * 4 + reg) * 72 + nt * 16 + n15] =
              f2bf(silu1(acc[mt][nt][reg]));

    // layer 2: K=64 in 2 steps; no outer activation
    floatx4 o[4][4];
#pragma unroll
    for (int mt = 0; mt < 4; ++mt)
#pragma unroll
      for (int nt = 0; nt < 4; ++nt) {
        float bv = cb2[nt * 16 + n15];
#pragma unroll
        for (int reg = 0; reg < 4; ++reg) o[mt][nt][reg] = bv;
      }
#pragma unroll
    for (int ks = 0; ks < 2; ++ks) {
      short8 B[4];
#pragma unroll
      for (int nt = 0; nt < 4; ++nt)
        B[nt] = *(const short8*)&w2b[((ks * 4 + quad) * 64 + nt * 16 + n15) * 8];
#pragma unroll
      for (int mt = 0; mt < 4; ++mt) {
        short8 A = *(const short8*)&hm[(mt * 16 + n15) * 72 + ks * 32 + quad * 8];
#pragma unroll
        for (int nt = 0; nt < 4; ++nt)
          o[mt][nt] = MFMA16(A, B[nt], o[mt][nt]);
      }
    }

#pragma unroll
    for (int mt = 0; mt < 4; ++mt)
#pragma unroll
      for (int reg = 0; reg < 4; ++reg) {
        const int row = base + mt * 16 + quad * 4 + reg;
        if (row < N) {
#pragma unroll
          for (int nt = 0; nt < 4; ++nt)
            outp[(size_t)row * 64 + nt * 16 + n15] = o[mt][nt][reg];
        }
      }
  }
}

// ================= node kernel: pe update MLP via MFMA =================
// upe_in = [pe, aggr_pos] (K=128), tanh inner AND outer.
__global__ __launch_bounds__(256, 2) void knode_upe(
    const ushort_t* __restrict__ peb,
    const float* aggrp,
    const float* __restrict__ w1, const float* __restrict__ b1,
    const float* __restrict__ w2, const float* __restrict__ b2,
    float* outp, int N) {
  __shared__ ushort_t w1b[8192];           // 16 KB: 128 k-rows
  __shared__ ushort_t w2b[4096];           // 8 KB
  __shared__ ushort_t hmat[4][4608];       // 36.9 KB
  __shared__ float cb1[64], cb2[64];

  for (int i = threadIdx.x; i < 128 * 64; i += 256) {
    int k = i >> 6, n = i & 63;
    w1b[(((k >> 5) * 4 + ((k >> 3) & 3)) * 64 + n) * 8 + (k & 7)] = f2bf(w1[i]);
  }
  for (int i = threadIdx.x; i < 64 * 64; i += 256) {
    int k = i >> 6, n = i & 63;
    w2b[(((k >> 5) * 4 + ((k >> 3) & 3)) * 64 + n) * 8 + (k & 7)] = f2bf(w2[i]);
  }
  if (threadIdx.x < 64) { cb1[threadIdx.x] = b1[threadIdx.x]; cb2[threadIdx.x] = b2[threadIdx.x]; }
  __syncthreads();

  const int lane = threadIdx.x & 63;
  const int wv   = threadIdx.x >> 6;
  const int n15  = lane & 15;
  const int quad = lane >> 4;
  const int gw   = blockIdx.x * 4 + wv;
  ushort_t* hm = &hmat[wv][0];

  for (int base = gw * 64; base < N; base += gridDim.x * 256) {
    floatx4 acc[4][4];
#pragma unroll
    for (int mt = 0; mt < 4; ++mt)
#pragma unroll
      for (int nt = 0; nt < 4; ++nt) {
        float bv = cb1[nt * 16 + n15];
#pragma unroll
        for (int reg = 0; reg < 4; ++reg) acc[mt][nt][reg] = bv;
      }

    // layer 1: K=128 in 4 steps of 32 (seg 0: pe, 1: aggrp fp32->bf16)
#pragma unroll
    for (int ks = 0; ks < 4; ++ks) {
      const int seg = ks >> 1, half = ks & 1;
      short8 B[4];
#pragma unroll
      for (int nt = 0; nt < 4; ++nt)
        B[nt] = *(const short8*)&w1b[((ks * 4 + quad) * 64 + nt * 16 + n15) * 8];
#pragma unroll
      for (int mt = 0; mt < 4; ++mt) {
        int row = min(base + mt * 16 + n15, N - 1);
        short8 A;
        if (seg == 0) {
          A = *(const short8*)(peb + (size_t)row * 64 + half * 32 + quad * 8);
        } else {
          const float* ap = aggrp + (size_t)row * 64 + half * 32 + quad * 8;
          float4 f0 = *(const float4*)ap;
          float4 f1 = *(const float4*)(ap + 4);
          union { ushort_t u[8]; short8 s; } pk;
          pk.u[0] = f2bf(f0.x); pk.u[1] = f2bf(f0.y); pk.u[2] = f2bf(f0.z); pk.u[3] = f2bf(f0.w);
          pk.u[4] = f2bf(f1.x); pk.u[5] = f2bf(f1.y); pk.u[6] = f2bf(f1.z); pk.u[7] = f2bf(f1.w);
          A = pk.s;
        }
#pragma unroll
        for (int nt = 0; nt < 4; ++nt)
          acc[mt][nt] = MFMA16(A, B[nt], acc[mt][nt]);
      }
    }

    // epilogue 1: tanh -> bf16 h-matrix
#pragma unroll
    for (int mt = 0; mt < 4; ++mt)
#pragma unroll
      for (int nt = 0; nt < 4; ++nt)
#pragma unroll
        for (int reg = 0; reg < 4; ++reg)
          hm[(mt * 16 + quad * 4 + reg) * 72 + nt * 16 + n15] =
              f2bf(tanh1(acc[mt][nt][reg]));

    // layer 2: K=64 in 2 steps; outer tanh
    floatx4 o[4][4];
#pragma unroll
    for (int mt = 0; mt < 4; ++mt)
#pragma unroll
      for (int nt = 0; nt < 4; ++nt) {
        float bv = cb2[nt * 16 + n15];
#pragma unroll
        for (int reg = 0; reg < 4; ++reg) o[mt][nt][reg] = bv;
      }
#pragma unroll
    for (int ks = 0; ks < 2; ++ks) {
      short8 B[4];
#pragma unroll
      for (int nt = 0; nt < 4; ++nt)
        B[nt] = *(const short8*)&w2b[((ks * 4 + quad) * 64 + nt * 16 + n15) * 8];
#pragma unroll
      for (int mt = 0; mt < 4; ++mt) {
        short8 A = *(const short8*)&hm[(mt * 16 + n15) * 72 + ks * 32 + quad * 8];
#pragma unroll
        for (int nt = 0; nt < 4; ++nt)
          o[mt][nt] = MFMA16(A, B[nt], o[mt][nt]);
      }
    }

#pragma unroll
    for (int mt = 0; mt < 4; ++mt)
#pragma unroll
      for (int reg = 0; reg < 4; ++reg) {
        const int row = base + mt * 16 + quad * 4 + reg;
        if (row < N) {
#pragma unroll
          for (int nt = 0; nt < 4; ++nt)
            outp[(size_t)row * 64 + nt * 16 + n15] = tanh1(o[mt][nt][reg]);
        }
      }
  }
}

extern "C" void kernel_launch(void* const* d_in, const int* in_sizes, int n_in,
                              void* d_out, int out_size, void* d_ws, size_t ws_size,
                              hipStream_t stream) {
  const float* x    = (const float*)d_in[0];
  const float* pos  = (const float*)d_in[1];
  const float* pe   = (const float*)d_in[2];
  const int*   eidx = (const int*)d_in[3];
  const float* msg_w1  = (const float*)d_in[4];
  const float* msg_b1  = (const float*)d_in[5];
  const float* msg_w2  = (const float*)d_in[6];
  const float* msg_b2  = (const float*)d_in[7];
  const float* mpos_w1 = (const float*)d_in[8];
  const float* mpos_b1 = (const float*)d_in[9];
  const float* mpos_w2 = (const float*)d_in[10];
  const float* mpos_b2 = (const float*)d_in[11];
  const float* upd_w1  = (const float*)d_in[12];
  const float* upd_b1  = (const float*)d_in[13];
  const float* upd_w2  = (const float*)d_in[14];
  const float* upd_b2  = (const float*)d_in[15];
  const float* upe_w1  = (const float*)d_in[16];
  const float* upe_b1  = (const float*)d_in[17];
  const float* upe_w2  = (const float*)d_in[18];
  const float* upe_b2  = (const float*)d_in[19];

  const int N = in_sizes[0] / HDIM;
  const int E = in_sizes[3] / 2;

  float* out_upd = (float*)d_out;                 // aggr accumulator, then update out
  float* out_upe = out_upd + (size_t)N * HDIM;    // aggr_pos accumulator, then update_pe out

  // workspace layout: xb | peb | cnt | sedge
  ushort_t* xb   = (ushort_t*)d_ws;
  ushort_t* peb  = xb + (size_t)N * HDIM;
  int*      cnt  = (int*)(peb + (size_t)N * HDIM);
  int2*     sedge = (int2*)(cnt + N);

  hipMemsetAsync(d_out, 0, (size_t)2 * N * HDIM * sizeof(float), stream);
  hipMemsetAsync(cnt, 0, (size_t)N * sizeof(int), stream);

  const int ncv = N * HDIM;
  kcvt2<<<(2 * ncv / 8 + 255) / 256, 256, 0, stream>>>(x, pe, xb, ncv);

  // counting sort of edges by receiver
  khist<<<2048, 256, 0, stream>>>(eidx, cnt, E);
  kscan<<<1, 1024, 0, stream>>>(cnt, N);
  kscatter<<<2048, 256, 0, stream>>>(eidx, cnt, sedge, E);

  kedge<<<512, 256, 0, stream>>>(xb, peb, pos, sedge,
                                 msg_w1, msg_b1, msg_w2, msg_b2,
                                 mpos_w1, mpos_b1, mpos_w2, mpos_b2,
                                 out_upd, out_upe, E);

  // node kernels: one 64-node tile per wave -> grid = ceil(ceil(N/64)/4)
  const int ntiles = (N + 63) / 64;
  const int ngrid  = (ntiles + 3) / 4;
  knode_upd<<<ngrid, 256, 0, stream>>>(xb, peb, out_upd, upd_w1, upd_b1, upd_w2, upd_b2,
                                       out_upd, N);
  knode_upe<<<ngrid, 256, 0, stream>>>(peb, out_upe, upe_w1, upe_b1, upe_w2, upe_b2,
                                       out_upe, N);
}